// Round 15
// baseline (216.310 us; speedup 1.0000x reference)
//
#include <hip/hip_runtime.h>
#include <hip/hip_bf16.h>
#include <cstdint>
#include <cstddef>

typedef __attribute__((ext_vector_type(4))) float f32x4;
typedef __attribute__((ext_vector_type(16))) float f32x16;
typedef __attribute__((ext_vector_type(8))) short bf16x8;
typedef unsigned int u32;
typedef unsigned short u16;

// ---------- helpers ----------

__device__ __forceinline__ u16 f2bf(float x) {
  u32 u = __builtin_bit_cast(u32, x);
  u += 0x7fffu + ((u >> 16) & 1u);   // round-to-nearest-even
  return (u16)(u >> 16);
}

__device__ __forceinline__ u32 cvt_pk_bf16(float lo, float hi) {
  u32 r;
  asm("v_cvt_pk_bf16_f32 %0, %1, %2" : "=v"(r) : "v"(lo), "v"(hi));
  return r;
}

// raw 2^x (trans op; s_nop guards the trans->VALU hazard window)
__device__ __forceinline__ float fexp2(float x) {
  float r;
  asm("v_exp_f32 %0, %1\n\ts_nop 1" : "=v"(r) : "v"(x));
  return r;
}

// v_permlane32_swap_b32: a' = [a.lo | b.lo], b' = [a.hi | b.hi]
__device__ __forceinline__ void perm_swap(u32& a, u32& b) {
  asm("v_permlane32_swap_b32 %0, %1" : "+v"(a), "+v"(b));
}

// async global->LDS, 16B per lane. Dest must be wave-linear (base + lane*16).
__device__ __forceinline__ void gl_lds16(const void* g, void* l) {
  __builtin_amdgcn_global_load_lds(
      (const __attribute__((address_space(1))) u32*)(uintptr_t)g,
      (__attribute__((address_space(3))) u32*)(u32)(uintptr_t)l,
      16, 0, 0);
}

#define MFMA16(a, b, c) __builtin_amdgcn_mfma_f32_16x16x32_bf16((a), (b), (c), 0, 0, 0)
#define MFMA32(a, b, c) __builtin_amdgcn_mfma_f32_32x32x16_bf16((a), (b), (c), 0, 0, 0)
#define SBAR() do { __builtin_amdgcn_sched_barrier(0); __builtin_amdgcn_s_barrier(); \
                    __builtin_amdgcn_sched_barrier(0); } while (0)
#define SCHED_FENCE() __builtin_amdgcn_sched_barrier(0)

// ---------- fused cast fp32 -> bf16 for x + 4 weights ----------

__global__ void cast_all_k(const float* __restrict__ x, const float* __restrict__ wq,
                           const float* __restrict__ wk, const float* __restrict__ wv,
                           const float* __restrict__ wo, u16* __restrict__ xb,
                           u16* __restrict__ wqb, u16* __restrict__ wkb,
                           u16* __restrict__ wvb, u16* __restrict__ wob) {
  int blk = blockIdx.x;
  const float* s; u16* d; int i;
  if (blk < 8192)       { s = x;  d = xb;  i = blk * 256; }
  else if (blk < 9216)  { s = wq; d = wqb; i = (blk - 8192) * 256; }
  else if (blk < 10240) { s = wk; d = wkb; i = (blk - 9216) * 256; }
  else if (blk < 11264) { s = wv; d = wvb; i = (blk - 10240) * 256; }
  else                  { s = wo; d = wob; i = (blk - 11264) * 256; }
  i += threadIdx.x;
  const float4 v = reinterpret_cast<const float4*>(s)[i];
  uint2 o;
  o.x = cvt_pk_bf16(v.x, v.y);
  o.y = cvt_pk_bf16(v.z, v.w);
  reinterpret_cast<uint2*>(d)[i] = o;
}

// ---------- rope cos/sin table: [S][32] of float2(cos,sin) ----------

__global__ void rope_table_k(const int* __restrict__ pos, float2* __restrict__ cs) {
  int idx = blockIdx.x * 256 + threadIdx.x;   // S*32 = 65536
  int s = idx >> 5, i = idx & 31;
  float inv = powf(10000.0f, -(float)i * (1.0f / 32.0f));
  float ang = (float)pos[s] * inv;
  cs[idx] = float2{cosf(ang), sinf(ang)};
}

// ---------- fused QKV GEMM — 256x256, BK=64, 4-subphase interleave ----------

__global__ __launch_bounds__(512)
void gemm_qkv(const u16* __restrict__ A, const u16* __restrict__ B,
              const float2* __restrict__ cs, u16* __restrict__ Qr,
              u16* __restrict__ Kr, u16* __restrict__ Vt, float qscale) {
  const int K = 1024;
  __shared__ u16 a_lds[2][256 * 64];
  __shared__ u16 b_lds[2][256 * 64];

  const int tid = threadIdx.x, l = tid & 63;
  const int wid = tid >> 6;                // 0..7
  const int wr = wid >> 2, wc = wid & 3;   // wave tile 128 rows x 64 cols
  const int c = l & 15, h4 = l >> 4;

  // XCD swizzle: id&7 = XCD; bm = xcd*4 + k/12, bn = k%12
  const int id = blockIdx.x;               // 384
  const int k48 = id >> 3, xcd = id & 7;
  const int bm = xcd * 4 + k48 / 12, bn = k48 % 12;

  const u16* Ab = A + (size_t)bm * 256 * K;
  const u16* Bb = B + (size_t)bn * 256 * K;

  auto stageA = [&](int s, int chunk, int k0) {
    int t5 = chunk * 512 + tid;
    int row = t5 >> 3, slot = t5 & 7;
    int sp = slot ^ (row & 7);
    gl_lds16(Ab + (size_t)row * K + k0 + sp * 8, &a_lds[s][t5 * 8]);
  };
  auto stageB = [&](int s, int chunk, int k0) {
    int t5 = chunk * 512 + tid;
    int row = t5 >> 3, slot = t5 & 7;
    int sp = slot ^ (row & 7);
    gl_lds16(Bb + (size_t)row * K + k0 + sp * 8, &b_lds[s][t5 * 8]);
  };

  const f32x4 fz = {0.f, 0.f, 0.f, 0.f};
  f32x4 acc[8][4];
#pragma unroll
  for (int mi = 0; mi < 8; ++mi)
#pragma unroll
    for (int ni = 0; ni < 4; ++ni) acc[mi][ni] = fz;

  // prologue: stage tile 0 fully, drain, barrier
#pragma unroll
  for (int ch = 0; ch < 4; ++ch) stageA(0, ch, 0);
#pragma unroll
  for (int ch = 0; ch < 4; ++ch) stageB(0, ch, 0);
  asm volatile("s_waitcnt vmcnt(0)" ::: "memory");
  SBAR();

  const int nk = K >> 6;                   // 16 K-tiles
#pragma unroll 1
  for (int t = 0; t < nk; ++t) {
    const int s = t & 1;
    const int k1 = (t + 1) << 6;
    const bool st = (t + 1 < nk);

    bf16x8 bfr[4][2];
#pragma unroll
    for (int ni = 0; ni < 4; ++ni)
#pragma unroll
      for (int kk = 0; kk < 2; ++kk) {
        int row = wc * 64 + ni * 16 + c;
        int sp = (kk * 4 + h4) ^ (row & 7);
        bfr[ni][kk] = *(const bf16x8*)&b_lds[s][row * 64 + sp * 8];
      }

#pragma unroll
    for (int p = 0; p < 4; ++p) {
      bf16x8 af[2][2];
#pragma unroll
      for (int m2 = 0; m2 < 2; ++m2)
#pragma unroll
        for (int kk = 0; kk < 2; ++kk) {
          int mi = p * 2 + m2;
          int row = wr * 128 + mi * 16 + c;
          int sp = (kk * 4 + h4) ^ (row & 7);
          af[m2][kk] = *(const bf16x8*)&a_lds[s][row * 64 + sp * 8];
        }
      if (st) {
        if (p < 2) { stageA(s ^ 1, p * 2, k1); stageA(s ^ 1, p * 2 + 1, k1); }
        else       { stageB(s ^ 1, (p - 2) * 2, k1); stageB(s ^ 1, (p - 2) * 2 + 1, k1); }
      }
      SCHED_FENCE();
      __builtin_amdgcn_s_setprio(1);
#pragma unroll
      for (int m2 = 0; m2 < 2; ++m2)
#pragma unroll
        for (int ni = 0; ni < 4; ++ni)
#pragma unroll
          for (int kk = 0; kk < 2; ++kk)
            acc[p * 2 + m2][ni] = MFMA16(af[m2][kk], bfr[ni][kk], acc[p * 2 + m2][ni]);
      __builtin_amdgcn_s_setprio(0);
      SCHED_FENCE();
    }

    asm volatile("s_waitcnt vmcnt(0)" ::: "memory");   // tile t+1 staged
    SBAR();
  }

  // ---- epilogue: sector 0->Q(rope) 1->K(rope) 2->V(T) ----
  const int sector = bn >> 2;
  const int colb = ((bn & 3) << 8) + wc * 64;

  if (sector == 2) {
#pragma unroll
    for (int mi = 0; mi < 8; ++mi) {
      int row = bm * 256 + wr * 128 + mi * 16 + 4 * h4;
      int b_ = row >> 11, s = row & 2047;
#pragma unroll
      for (int ni = 0; ni < 4; ++ni) {
        int cv = colb + ni * 16 + c;
        int hh = cv >> 6, dk = cv & 63;
        f32x4 v = acc[mi][ni];
        uint2 st;
        st.x = cvt_pk_bf16(v[0], v[1]);
        st.y = cvt_pk_bf16(v[2], v[3]);
        *(uint2*)&Vt[(((size_t)b_ * 16 + hh) << 17) + ((size_t)dk << 11) + s] = st;
      }
    }
  } else {
    u16* dst = sector ? Kr : Qr;
    const float scale = sector ? 1.0f : qscale;
#pragma unroll
    for (int mi = 0; mi < 8; ++mi) {
      int row0 = bm * 256 + wr * 128 + mi * 16 + 4 * h4;
#pragma unroll
      for (int ni = 0; ni < 4; ++ni) {
        int cv = colb + ni * 16 + c;
        int hh = cv >> 6, i2 = cv & 63;
        f32x4 v = acc[mi][ni];
        f32x4 pv;
#pragma unroll
        for (int j = 0; j < 4; ++j) pv[j] = __shfl_xor(v[j], 1);
        if (!(l & 1)) {
#pragma unroll
          for (int j = 0; j < 4; ++j) {
            int r = row0 + j, s = r & 2047, b_ = r >> 11;
            float2 tt = cs[(s << 5) + (i2 >> 1)];
            float oe = (v[j] * tt.x - pv[j] * tt.y) * scale;
            float oo = (v[j] * tt.y + pv[j] * tt.x) * scale;
            *(u32*)&dst[(((size_t)(b_ * 16 + hh) * 2048 + s) << 6) + i2] =
                cvt_pk_bf16(oe, oo);
          }
        }
      }
    }
  }
}

// ---------- GEMM: C(MxN fp32) = A(MxK bf16) * B^T — 3-slot counted-vmcnt ----------

__global__ __launch_bounds__(256, 3)
void gemm_bt(const u16* __restrict__ A, const u16* __restrict__ B,
             float* __restrict__ C, int M, int N, int K) {
  __shared__ u16 a_lds[3][128 * 32];
  __shared__ u16 b_lds[3][128 * 32];
  const int tid = threadIdx.x;
  const int l = tid & 63;
  const int w = tid >> 6;
  const int wm = w >> 1, wn = w & 1;
  const int bm = blockIdx.y, bn = blockIdx.x;
  const int c = l & 15, h4 = l >> 4;

  const u16* Ab = A + (size_t)bm * 128 * K;
  const u16* Bb = B + (size_t)bn * 128 * K;

  auto stage = [&](int sl, int k0) {
#pragma unroll
    for (int half = 0; half < 2; ++half) {
      int t = half * 256 + tid;
      int row = t >> 2, slot = t & 3;
      int sp = slot ^ ((row >> 1) & 3);
      gl_lds16(Ab + (size_t)row * K + k0 + sp * 8, &a_lds[sl][t * 8]);
      gl_lds16(Bb + (size_t)row * K + k0 + sp * 8, &b_lds[sl][t * 8]);
    }
  };

  const f32x4 fz = {0.f, 0.f, 0.f, 0.f};
  f32x4 acc[4][4];
#pragma unroll
  for (int mi = 0; mi < 4; ++mi)
#pragma unroll
    for (int ni = 0; ni < 4; ++ni) acc[mi][ni] = fz;

  const int nk = K >> 5;
  stage(0, 0);
  stage(1, 32);

  int sl = 0;
#pragma unroll 1
  for (int t = 0; t < nk; ++t) {
    if (t + 2 < nk) {
      int s2 = sl + 2; if (s2 >= 3) s2 -= 3;
      stage(s2, (t + 2) * 32);
      __builtin_amdgcn_sched_barrier(0);
      asm volatile("s_waitcnt vmcnt(8)" ::: "memory");
    } else if (t + 1 < nk) {
      asm volatile("s_waitcnt vmcnt(4)" ::: "memory");
    } else {
      asm volatile("s_waitcnt vmcnt(0)" ::: "memory");
    }
    SBAR();

    bf16x8 af[4], bf[4];
#pragma unroll
    for (int mi = 0; mi < 4; ++mi) {
      int row = wm * 64 + mi * 16 + c;
      int sp = h4 ^ ((row >> 1) & 3);
      af[mi] = *(const bf16x8*)&a_lds[sl][row * 32 + sp * 8];
    }
#pragma unroll
    for (int ni = 0; ni < 4; ++ni) {
      int row = wn * 64 + ni * 16 + c;
      int sp = h4 ^ ((row >> 1) & 3);
      bf[ni] = *(const bf16x8*)&b_lds[sl][row * 32 + sp * 8];
    }
    __builtin_amdgcn_s_setprio(1);
#pragma unroll
    for (int mi = 0; mi < 4; ++mi)
#pragma unroll
      for (int ni = 0; ni < 4; ++ni)
        acc[mi][ni] = MFMA16(af[mi], bf[ni], acc[mi][ni]);
    __builtin_amdgcn_s_setprio(0);

    sl = (sl == 2) ? 0 : sl + 1;
  }

#pragma unroll
  for (int mi = 0; mi < 4; ++mi) {
    int rbase = bm * 128 + wm * 64 + mi * 16 + ((l >> 4) << 2);
#pragma unroll
    for (int ni = 0; ni < 4; ++ni) {
      int col = bn * 128 + wn * 64 + ni * 16 + (l & 15);
      f32x4 v = acc[mi][ni];
#pragma unroll
      for (int j = 0; j < 4; ++j)
        C[(size_t)(rbase + j) * N + col] = v[j];
    }
  }
}

// ---------- causal flash attention: 2-wave blocks, 64 q-rows, 4 blocks/CU ----------
// Pairing (g, 31-g) over 64-row q-groups -> every block exactly 33 KV tiles.
// Grid 1024 (128 thr) = exactly 4 blocks/CU, one round, XCD-swizzled.
// 2-slot LDS (32KB), protocol: vmcnt(0) -> s_barrier -> stage(t+1) -> compute(t).
// (WAR-safe: passing barrier t implies all waves finished compute(t-1).)
// Only the final tile (t == nt-1) needs causal masking (q-range == tile width).

__global__ __launch_bounds__(128)
void attn_k(const u16* __restrict__ Q, const u16* __restrict__ K,
            const u16* __restrict__ V, u16* __restrict__ O) {
  const int S = 2048;
  __shared__ u16 k_lds[2][64 * 64];
  __shared__ u16 v_lds[2][64 * 64];       // [dk][kv]

  const int tid = threadIdx.x, l = tid & 63, w = tid >> 6;   // w in 0..1
  const int lane31 = l & 31, hi = l >> 5;

  // XCD swizzle: 128 consecutive idx per XCD -> 8 bh per XCD
  const int wg = blockIdx.x;                       // 1024
  const int idx = (wg & 7) * 128 + (wg >> 3);
  const int bh = idx >> 4, pairI = idx & 15;

  const u16* Kb = K + (size_t)bh * S * 64;
  const u16* Vb = V + (size_t)bh * 64 * S;
  const int b = bh >> 4, hd = bh & 15;

  auto stageKV = [&](int bq, int kv0) {
#pragma unroll
    for (int ch = 0; ch < 4; ++ch) {
      int t5 = ch * 128 + tid;                     // 0..511
      int row = t5 >> 3, slot = t5 & 7;
      int sp = slot ^ (row & 7);
      gl_lds16(Kb + (size_t)(kv0 + row) * 64 + sp * 8, &k_lds[bq][t5 * 8]);
      gl_lds16(Vb + (size_t)row * S + kv0 + sp * 8, &v_lds[bq][t5 * 8]);
    }
  };

#pragma unroll 1
  for (int ph = 0; ph < 2; ++ph) {
    const int g = ph ? (31 - pairI) : pairI;       // 64-row q-group
    const int q0 = g * 64;
    const int nt = g + 1;
    const int qrow = q0 + w * 32 + lane31;
    const u16* Qp = Q + ((size_t)bh * S + qrow) * 64;

    bf16x8 qf[4];
#pragma unroll
    for (int ks = 0; ks < 4; ++ks)
      qf[ks] = *(const bf16x8*)(Qp + ks * 16 + hi * 8);
    __builtin_amdgcn_sched_barrier(0);
    stageKV(0, 0);

    f32x16 oacc[2];
#pragma unroll
    for (int dt = 0; dt < 2; ++dt)
#pragma unroll
      for (int r = 0; r < 16; ++r) oacc[dt][r] = 0.f;
    float m_run = -1e30f, l_run = 0.f;

    int slot = 0;
#pragma unroll 1
    for (int t = 0; t < nt; ++t) {
      asm volatile("s_waitcnt vmcnt(0)" ::: "memory");   // own tile-t loads landed
      SBAR();                                            // all waves' tile-t landed
      if (t + 1 < nt) stageKV(slot ^ 1, (t + 1) * 64);   // WAR-safe after barrier
      __builtin_amdgcn_sched_barrier(0);

      // S^T = K * Q^T : C[kv, q]; per lane q = qrow
      f32x16 sc[2];
#pragma unroll
      for (int dt = 0; dt < 2; ++dt)
#pragma unroll
        for (int r = 0; r < 16; ++r) sc[dt][r] = 0.f;
      __builtin_amdgcn_s_setprio(1);
#pragma unroll
      for (int ks = 0; ks < 4; ++ks) {
        int sp = (2 * ks + hi) ^ (lane31 & 7);
#pragma unroll
        for (int dt = 0; dt < 2; ++dt) {
          bf16x8 kf = *(const bf16x8*)&k_lds[slot][(dt * 32 + lane31) * 64 + sp * 8];
          sc[dt] = MFMA32(kf, qf[ks], sc[dt]);
        }
      }
      __builtin_amdgcn_s_setprio(0);

      bf16x8 vf[2][4];
#pragma unroll
      for (int ks = 0; ks < 4; ++ks) {
        int sp = (2 * ks + hi) ^ (lane31 & 7);
#pragma unroll
        for (int dt = 0; dt < 2; ++dt)
          vf[dt][ks] = *(const bf16x8*)&v_lds[slot][(dt * 32 + lane31) * 64 + sp * 8];
      }

      // causal mask — only the diagonal (last) tile
      if (t == nt - 1) {
#pragma unroll
        for (int dt = 0; dt < 2; ++dt)
#pragma unroll
          for (int r = 0; r < 16; ++r) {
            int kvg = t * 64 + dt * 32 + (r & 3) + 8 * (r >> 2) + 4 * hi;
            if (kvg > qrow) sc[dt][r] = -1e30f;
          }
      }

      // online softmax — tree max, raw exp, tree sum; one cross-half shfl each
      float r16[16];
#pragma unroll
      for (int i = 0; i < 16; ++i) r16[i] = fmaxf(sc[0][i], sc[1][i]);
#pragma unroll
      for (int i = 0; i < 8; ++i) r16[i] = fmaxf(r16[i], r16[i + 8]);
#pragma unroll
      for (int i = 0; i < 4; ++i) r16[i] = fmaxf(r16[i], r16[i + 4]);
      float mx = fmaxf(fmaxf(r16[0], r16[1]), fmaxf(r16[2], r16[3]));
      mx = fmaxf(mx, __shfl_xor(mx, 32));

      const bool nores = __all(mx <= m_run);
      float mnew = nores ? m_run : fmaxf(m_run, mx);
#pragma unroll
      for (int dt = 0; dt < 2; ++dt)
#pragma unroll
        for (int r = 0; r < 16; ++r) sc[dt][r] = fexp2(sc[dt][r] - mnew);
      float s16[16];
#pragma unroll
      for (int i = 0; i < 16; ++i) s16[i] = sc[0][i] + sc[1][i];
#pragma unroll
      for (int i = 0; i < 8; ++i) s16[i] += s16[i + 8];
#pragma unroll
      for (int i = 0; i < 4; ++i) s16[i] += s16[i + 4];
      float ps = (s16[0] + s16[1]) + (s16[2] + s16[3]);
      ps += __shfl_xor(ps, 32);

      if (nores) {
        l_run += ps;
      } else {
        float alpha = fexp2(m_run - mnew);
        l_run = l_run * alpha + ps;
        m_run = mnew;
#pragma unroll
        for (int dt = 0; dt < 2; ++dt)
#pragma unroll
          for (int r = 0; r < 16; ++r) oacc[dt][r] *= alpha;
      }

      union { u32 u[4]; bf16x8 v; } pf[4];
#pragma unroll
      for (int ks = 0; ks < 4; ++ks) {
        const int sidx = ks >> 1, rb = (ks & 1) * 8;
        u32 c01 = cvt_pk_bf16(sc[sidx][rb + 0], sc[sidx][rb + 1]);
        u32 c23 = cvt_pk_bf16(sc[sidx][rb + 2], sc[sidx][rb + 3]);
        u32 c45 = cvt_pk_bf16(sc[sidx][rb + 4], sc[sidx][rb + 5]);
        u32 c67 = cvt_pk_bf16(sc[sidx][rb + 6], sc[sidx][rb + 7]);
        perm_swap(c01, c45);
        perm_swap(c23, c67);
        pf[ks].u[0] = c01; pf[ks].u[1] = c23; pf[ks].u[2] = c45; pf[ks].u[3] = c67;
      }

      __builtin_amdgcn_s_setprio(1);
#pragma unroll
      for (int dt = 0; dt < 2; ++dt)
#pragma unroll
        for (int ks = 0; ks < 4; ++ks)
          oacc[dt] = MFMA32(vf[dt][ks], pf[ks].v, oacc[dt]);
      __builtin_amdgcn_s_setprio(0);

      slot ^= 1;
    }

    SBAR();   // all waves done with both slots before next phase restages

    float inv = 1.f / l_run;
    u16* Ob = O + (((size_t)(b * 2048 + qrow)) << 10) + hd * 64;
#pragma unroll
    for (int dt = 0; dt < 2; ++dt)
#pragma unroll
      for (int g2 = 0; g2 < 4; ++g2) {
        uint2 st;
        st.x = cvt_pk_bf16(oacc[dt][4 * g2 + 0] * inv, oacc[dt][4 * g2 + 1] * inv);
        st.y = cvt_pk_bf16(oacc[dt][4 * g2 + 2] * inv, oacc[dt][4 * g2 + 3] * inv);
        *(uint2*)&Ob[dt * 32 + g2 * 8 + hi * 4] = st;
      }
  }
}

// ---------- launch ----------

extern "C" void kernel_launch(void* const* d_in, const int* in_sizes, int n_in,
                              void* d_out, int out_size, void* d_ws, size_t ws_size,
                              hipStream_t stream) {
  (void)in_sizes; (void)n_in; (void)out_size; (void)ws_size;
  const float* x  = (const float*)d_in[0];
  const int* pos  = (const int*)d_in[1];
  const float* Wq = (const float*)d_in[2];
  const float* Wk = (const float*)d_in[3];
  const float* Wv = (const float*)d_in[4];
  const float* Wo = (const float*)d_in[5];
  float* out = (float*)d_out;

  const int S = 2048, D = 1024;
  const size_t M = (size_t)4 * S;          // 8192

  char* ws = (char*)d_ws;
  size_t off = 0;
  auto alloc = [&](size_t bytes) {
    void* p = ws + off;
    off += (bytes + 255) & ~(size_t)255;
    return p;
  };
  u16* xb   = (u16*)alloc(M * D * 2);
  u16* wqb  = (u16*)alloc((size_t)D * D * 2);   // wqb|wkb|wvb|wob contiguous
  u16* wkb  = (u16*)alloc((size_t)D * D * 2);
  u16* wvb  = (u16*)alloc((size_t)D * D * 2);
  u16* wob  = (u16*)alloc((size_t)D * D * 2);
  u16* Qr   = (u16*)alloc(M * D * 2);
  u16* Kr   = (u16*)alloc(M * D * 2);
  u16* Vt   = (u16*)alloc(M * D * 2);
  u16* Ob   = (u16*)alloc(M * D * 2);
  float2* csT = (float2*)alloc((size_t)S * 32 * 8);

  cast_all_k<<<12288, 256, 0, stream>>>(x, Wq, Wk, Wv, Wo, xb, wqb, wkb, wvb, wob);
  rope_table_k<<<(S * 32) / 256, 256, 0, stream>>>(pos, csT);

  // Q scale: 1/sqrt(64) folded with 1/ln2 so attention logits are in exp2 domain
  const float QSCALE = 0.125f * 1.4426950408889634f;

  gemm_qkv<<<384, 512, 0, stream>>>(xb, wqb, csT, Qr, Kr, Vt, QSCALE);
  attn_k<<<1024, 128, 0, stream>>>(Qr, Kr, Vt, Ob);
  gemm_bt<<<dim3(8, (unsigned)(M / 128)), 256, 0, stream>>>(Ob, wob, out, (int)M, D, D);
}

// Round 16
// 180.596 us; speedup vs baseline: 1.1978x; 1.1978x over previous
//
#include <hip/hip_runtime.h>
#include <hip/hip_bf16.h>
#include <cstdint>
#include <cstddef>

typedef __attribute__((ext_vector_type(4))) float f32x4;
typedef __attribute__((ext_vector_type(16))) float f32x16;
typedef __attribute__((ext_vector_type(8))) short bf16x8;
typedef unsigned int u32;
typedef unsigned short u16;

// ---------- helpers ----------

__device__ __forceinline__ u16 f2bf(float x) {
  u32 u = __builtin_bit_cast(u32, x);
  u += 0x7fffu + ((u >> 16) & 1u);   // round-to-nearest-even
  return (u16)(u >> 16);
}

__device__ __forceinline__ u32 cvt_pk_bf16(float lo, float hi) {
  u32 r;
  asm("v_cvt_pk_bf16_f32 %0, %1, %2" : "=v"(r) : "v"(lo), "v"(hi));
  return r;
}

// raw 2^x (trans op; s_nop guards the trans->VALU hazard window)
__device__ __forceinline__ float fexp2(float x) {
  float r;
  asm("v_exp_f32 %0, %1\n\ts_nop 1" : "=v"(r) : "v"(x));
  return r;
}

// v_permlane32_swap_b32: a' = [a.lo | b.lo], b' = [a.hi | b.hi]
__device__ __forceinline__ void perm_swap(u32& a, u32& b) {
  asm("v_permlane32_swap_b32 %0, %1" : "+v"(a), "+v"(b));
}

// async global->LDS, 16B per lane. Dest must be wave-linear (base + lane*16).
__device__ __forceinline__ void gl_lds16(const void* g, void* l) {
  __builtin_amdgcn_global_load_lds(
      (const __attribute__((address_space(1))) u32*)(uintptr_t)g,
      (__attribute__((address_space(3))) u32*)(u32)(uintptr_t)l,
      16, 0, 0);
}

#define MFMA16(a, b, c) __builtin_amdgcn_mfma_f32_16x16x32_bf16((a), (b), (c), 0, 0, 0)
#define MFMA32(a, b, c) __builtin_amdgcn_mfma_f32_32x32x16_bf16((a), (b), (c), 0, 0, 0)
#define SBAR() do { __builtin_amdgcn_sched_barrier(0); __builtin_amdgcn_s_barrier(); \
                    __builtin_amdgcn_sched_barrier(0); } while (0)
#define SCHED_FENCE() __builtin_amdgcn_sched_barrier(0)

// ---------- fused cast fp32 -> bf16 for x + 4 weights ----------

__global__ void cast_all_k(const float* __restrict__ x, const float* __restrict__ wq,
                           const float* __restrict__ wk, const float* __restrict__ wv,
                           const float* __restrict__ wo, u16* __restrict__ xb,
                           u16* __restrict__ wqb, u16* __restrict__ wkb,
                           u16* __restrict__ wvb, u16* __restrict__ wob) {
  int blk = blockIdx.x;
  const float* s; u16* d; int i;
  if (blk < 8192)       { s = x;  d = xb;  i = blk * 256; }
  else if (blk < 9216)  { s = wq; d = wqb; i = (blk - 8192) * 256; }
  else if (blk < 10240) { s = wk; d = wkb; i = (blk - 9216) * 256; }
  else if (blk < 11264) { s = wv; d = wvb; i = (blk - 10240) * 256; }
  else                  { s = wo; d = wob; i = (blk - 11264) * 256; }
  i += threadIdx.x;
  const float4 v = reinterpret_cast<const float4*>(s)[i];
  uint2 o;
  o.x = cvt_pk_bf16(v.x, v.y);
  o.y = cvt_pk_bf16(v.z, v.w);
  reinterpret_cast<uint2*>(d)[i] = o;
}

// ---------- rope cos/sin table: [S][32] of float2(cos,sin) ----------

__global__ void rope_table_k(const int* __restrict__ pos, float2* __restrict__ cs) {
  int idx = blockIdx.x * 256 + threadIdx.x;   // S*32 = 65536
  int s = idx >> 5, i = idx & 31;
  float inv = powf(10000.0f, -(float)i * (1.0f / 32.0f));
  float ang = (float)pos[s] * inv;
  cs[idx] = float2{cosf(ang), sinf(ang)};
}

// ---------- fused QKV GEMM — 256x256, BK=64, top-wait pipeline ----------
// Protocol: at tile top, vmcnt(0) waits ONLY on tile-t chunks issued a full
// compute-tile earlier (latency hidden); s_barrier; then stage tile t+1
// (WAR-safe post-barrier) interleaved with 4 MFMA phases. NO end-of-tile drain.

__global__ __launch_bounds__(512)
void gemm_qkv(const u16* __restrict__ A, const u16* __restrict__ B,
              const float2* __restrict__ cs, u16* __restrict__ Qr,
              u16* __restrict__ Kr, u16* __restrict__ Vt, float qscale) {
  const int K = 1024;
  __shared__ u16 a_lds[2][256 * 64];
  __shared__ u16 b_lds[2][256 * 64];

  const int tid = threadIdx.x, l = tid & 63;
  const int wid = tid >> 6;                // 0..7
  const int wr = wid >> 2, wc = wid & 3;   // wave tile 128 rows x 64 cols
  const int c = l & 15, h4 = l >> 4;

  // XCD swizzle: id&7 = XCD; bm = xcd*4 + k/12, bn = k%12
  const int id = blockIdx.x;               // 384
  const int k48 = id >> 3, xcd = id & 7;
  const int bm = xcd * 4 + k48 / 12, bn = k48 % 12;

  const u16* Ab = A + (size_t)bm * 256 * K;
  const u16* Bb = B + (size_t)bn * 256 * K;

  auto stageA = [&](int s, int chunk, int k0) {
    int t5 = chunk * 512 + tid;
    int row = t5 >> 3, slot = t5 & 7;
    int sp = slot ^ (row & 7);
    gl_lds16(Ab + (size_t)row * K + k0 + sp * 8, &a_lds[s][t5 * 8]);
  };
  auto stageB = [&](int s, int chunk, int k0) {
    int t5 = chunk * 512 + tid;
    int row = t5 >> 3, slot = t5 & 7;
    int sp = slot ^ (row & 7);
    gl_lds16(Bb + (size_t)row * K + k0 + sp * 8, &b_lds[s][t5 * 8]);
  };

  const f32x4 fz = {0.f, 0.f, 0.f, 0.f};
  f32x4 acc[8][4];
#pragma unroll
  for (int mi = 0; mi < 8; ++mi)
#pragma unroll
    for (int ni = 0; ni < 4; ++ni) acc[mi][ni] = fz;

  // prologue: issue tile 0 (8 chunks); waited at loop top
#pragma unroll
  for (int ch = 0; ch < 4; ++ch) stageA(0, ch, 0);
#pragma unroll
  for (int ch = 0; ch < 4; ++ch) stageB(0, ch, 0);

  const int nk = K >> 6;                   // 16 K-tiles
#pragma unroll 1
  for (int t = 0; t < nk; ++t) {
    const int s = t & 1;
    const int k1 = (t + 1) << 6;
    const bool st = (t + 1 < nk);

    asm volatile("s_waitcnt vmcnt(0)" ::: "memory");  // own tile-t chunks landed
    SBAR();                                           // all waves' tile-t landed;
                                                      // all waves done reading t-1
    bf16x8 bfr[4][2];
#pragma unroll
    for (int ni = 0; ni < 4; ++ni)
#pragma unroll
      for (int kk = 0; kk < 2; ++kk) {
        int row = wc * 64 + ni * 16 + c;
        int sp = (kk * 4 + h4) ^ (row & 7);
        bfr[ni][kk] = *(const bf16x8*)&b_lds[s][row * 64 + sp * 8];
      }

#pragma unroll
    for (int p = 0; p < 4; ++p) {
      bf16x8 af[2][2];
#pragma unroll
      for (int m2 = 0; m2 < 2; ++m2)
#pragma unroll
        for (int kk = 0; kk < 2; ++kk) {
          int mi = p * 2 + m2;
          int row = wr * 128 + mi * 16 + c;
          int sp = (kk * 4 + h4) ^ (row & 7);
          af[m2][kk] = *(const bf16x8*)&a_lds[s][row * 64 + sp * 8];
        }
      if (st) {
        if (p < 2) { stageA(s ^ 1, p * 2, k1); stageA(s ^ 1, p * 2 + 1, k1); }
        else       { stageB(s ^ 1, (p - 2) * 2, k1); stageB(s ^ 1, (p - 2) * 2 + 1, k1); }
      }
      SCHED_FENCE();
      __builtin_amdgcn_s_setprio(1);
#pragma unroll
      for (int m2 = 0; m2 < 2; ++m2)
#pragma unroll
        for (int ni = 0; ni < 4; ++ni)
#pragma unroll
          for (int kk = 0; kk < 2; ++kk)
            acc[p * 2 + m2][ni] = MFMA16(af[m2][kk], bfr[ni][kk], acc[p * 2 + m2][ni]);
      __builtin_amdgcn_s_setprio(0);
      SCHED_FENCE();
    }
  }

  // ---- epilogue: sector 0->Q(rope) 1->K(rope) 2->V(T) ----
  const int sector = bn >> 2;
  const int colb = ((bn & 3) << 8) + wc * 64;

  if (sector == 2) {
#pragma unroll
    for (int mi = 0; mi < 8; ++mi) {
      int row = bm * 256 + wr * 128 + mi * 16 + 4 * h4;
      int b_ = row >> 11, s = row & 2047;
#pragma unroll
      for (int ni = 0; ni < 4; ++ni) {
        int cv = colb + ni * 16 + c;
        int hh = cv >> 6, dk = cv & 63;
        f32x4 v = acc[mi][ni];
        uint2 st;
        st.x = cvt_pk_bf16(v[0], v[1]);
        st.y = cvt_pk_bf16(v[2], v[3]);
        *(uint2*)&Vt[(((size_t)b_ * 16 + hh) << 17) + ((size_t)dk << 11) + s] = st;
      }
    }
  } else {
    u16* dst = sector ? Kr : Qr;
    const float scale = sector ? 1.0f : qscale;
#pragma unroll
    for (int mi = 0; mi < 8; ++mi) {
      int row0 = bm * 256 + wr * 128 + mi * 16 + 4 * h4;
#pragma unroll
      for (int ni = 0; ni < 4; ++ni) {
        int cv = colb + ni * 16 + c;
        int hh = cv >> 6, i2 = cv & 63;
        f32x4 v = acc[mi][ni];
        f32x4 pv;
#pragma unroll
        for (int j = 0; j < 4; ++j) pv[j] = __shfl_xor(v[j], 1);
        if (!(l & 1)) {
#pragma unroll
          for (int j = 0; j < 4; ++j) {
            int r = row0 + j, s = r & 2047, b_ = r >> 11;
            float2 tt = cs[(s << 5) + (i2 >> 1)];
            float oe = (v[j] * tt.x - pv[j] * tt.y) * scale;
            float oo = (v[j] * tt.y + pv[j] * tt.x) * scale;
            *(u32*)&dst[(((size_t)(b_ * 16 + hh) * 2048 + s) << 6) + i2] =
                cvt_pk_bf16(oe, oo);
          }
        }
      }
    }
  }
}

// ---------- GEMM: C(MxN fp32) = A(MxK bf16) * B^T — 3-slot counted-vmcnt ----------

__global__ __launch_bounds__(256, 3)
void gemm_bt(const u16* __restrict__ A, const u16* __restrict__ B,
             float* __restrict__ C, int M, int N, int K) {
  __shared__ u16 a_lds[3][128 * 32];
  __shared__ u16 b_lds[3][128 * 32];
  const int tid = threadIdx.x;
  const int l = tid & 63;
  const int w = tid >> 6;
  const int wm = w >> 1, wn = w & 1;
  const int bm = blockIdx.y, bn = blockIdx.x;
  const int c = l & 15, h4 = l >> 4;

  const u16* Ab = A + (size_t)bm * 128 * K;
  const u16* Bb = B + (size_t)bn * 128 * K;

  auto stage = [&](int sl, int k0) {
#pragma unroll
    for (int half = 0; half < 2; ++half) {
      int t = half * 256 + tid;
      int row = t >> 2, slot = t & 3;
      int sp = slot ^ ((row >> 1) & 3);
      gl_lds16(Ab + (size_t)row * K + k0 + sp * 8, &a_lds[sl][t * 8]);
      gl_lds16(Bb + (size_t)row * K + k0 + sp * 8, &b_lds[sl][t * 8]);
    }
  };

  const f32x4 fz = {0.f, 0.f, 0.f, 0.f};
  f32x4 acc[4][4];
#pragma unroll
  for (int mi = 0; mi < 4; ++mi)
#pragma unroll
    for (int ni = 0; ni < 4; ++ni) acc[mi][ni] = fz;

  const int nk = K >> 5;
  stage(0, 0);
  stage(1, 32);

  int sl = 0;
#pragma unroll 1
  for (int t = 0; t < nk; ++t) {
    if (t + 2 < nk) {
      int s2 = sl + 2; if (s2 >= 3) s2 -= 3;
      stage(s2, (t + 2) * 32);
      __builtin_amdgcn_sched_barrier(0);
      asm volatile("s_waitcnt vmcnt(8)" ::: "memory");
    } else if (t + 1 < nk) {
      asm volatile("s_waitcnt vmcnt(4)" ::: "memory");
    } else {
      asm volatile("s_waitcnt vmcnt(0)" ::: "memory");
    }
    SBAR();

    bf16x8 af[4], bf[4];
#pragma unroll
    for (int mi = 0; mi < 4; ++mi) {
      int row = wm * 64 + mi * 16 + c;
      int sp = h4 ^ ((row >> 1) & 3);
      af[mi] = *(const bf16x8*)&a_lds[sl][row * 32 + sp * 8];
    }
#pragma unroll
    for (int ni = 0; ni < 4; ++ni) {
      int row = wn * 64 + ni * 16 + c;
      int sp = h4 ^ ((row >> 1) & 3);
      bf[ni] = *(const bf16x8*)&b_lds[sl][row * 32 + sp * 8];
    }
    __builtin_amdgcn_s_setprio(1);
#pragma unroll
    for (int mi = 0; mi < 4; ++mi)
#pragma unroll
      for (int ni = 0; ni < 4; ++ni)
        acc[mi][ni] = MFMA16(af[mi], bf[ni], acc[mi][ni]);
    __builtin_amdgcn_s_setprio(0);

    sl = (sl == 2) ? 0 : sl + 1;
  }

#pragma unroll
  for (int mi = 0; mi < 4; ++mi) {
    int rbase = bm * 128 + wm * 64 + mi * 16 + ((l >> 4) << 2);
#pragma unroll
    for (int ni = 0; ni < 4; ++ni) {
      int col = bn * 128 + wn * 64 + ni * 16 + (l & 15);
      f32x4 v = acc[mi][ni];
#pragma unroll
      for (int j = 0; j < 4; ++j)
        C[(size_t)(rbase + j) * N + col] = v[j];
    }
  }
}

// ---------- causal flash attention: 32x32 MFMA, 4 waves, 3-slot pipeline ----------
// (reverted to the R12/R13-proven structure; + T13 defer-max RESCALE_THRESHOLD=8)

__global__ __launch_bounds__(256, 2)
void attn_k(const u16* __restrict__ Q, const u16* __restrict__ K,
            const u16* __restrict__ V, u16* __restrict__ O) {
  const int S = 2048;
  __shared__ u16 k_lds[3][64 * 64];
  __shared__ u16 v_lds[3][64 * 64];       // [dk][kv]

  const int tid = threadIdx.x, l = tid & 63, w = tid >> 6;
  const int lane31 = l & 31, hi = l >> 5;

  const int wg = blockIdx.x;                       // 512
  const int idx = (wg & 7) * 64 + (wg >> 3);
  const int bh = idx >> 3, pairI = idx & 7;

  const u16* Kb = K + (size_t)bh * S * 64;
  const u16* Vb = V + (size_t)bh * 64 * S;
  const int b = bh >> 4, hd = bh & 15;

  auto stageKV = [&](int bq, int kv0) {
#pragma unroll
    for (int half = 0; half < 2; ++half) {
      int t = half * 256 + tid;
      int row = t >> 3, slot = t & 7;
      int sp = slot ^ (row & 7);
      gl_lds16(Kb + (size_t)(kv0 + row) * 64 + sp * 8, &k_lds[bq][t * 8]);
      gl_lds16(Vb + (size_t)row * S + kv0 + sp * 8, &v_lds[bq][t * 8]);
    }
  };

#pragma unroll 1
  for (int ph = 0; ph < 2; ++ph) {
    const int qi = ph ? (15 - pairI) : pairI;
    const int q0 = qi * 128;
    const int nkv = 2 * qi + 2;
    const int qrow = q0 + w * 32 + lane31;
    const u16* Qp = Q + ((size_t)bh * S + qrow) * 64;

    bf16x8 qf[4];
#pragma unroll
    for (int ks = 0; ks < 4; ++ks)
      qf[ks] = *(const bf16x8*)(Qp + ks * 16 + hi * 8);
    __builtin_amdgcn_sched_barrier(0);
    stageKV(0, 0);
    stageKV(1, 64);

    f32x16 oacc[2];
#pragma unroll
    for (int dt = 0; dt < 2; ++dt)
#pragma unroll
      for (int r = 0; r < 16; ++r) oacc[dt][r] = 0.f;
    float m_run = -1e30f, l_run = 0.f;

    int buf = 0;
#pragma unroll 1
    for (int t = 0; t < nkv; ++t) {
      if (t + 2 < nkv) {
        int b2 = buf + 2; if (b2 >= 3) b2 -= 3;
        stageKV(b2, (t + 2) * 64);
        __builtin_amdgcn_sched_barrier(0);
        asm volatile("s_waitcnt vmcnt(8)" ::: "memory");
      } else if (t + 1 < nkv) {
        asm volatile("s_waitcnt vmcnt(4)" ::: "memory");
      } else {
        asm volatile("s_waitcnt vmcnt(0)" ::: "memory");
      }
      SBAR();

      f32x16 sc[2];
#pragma unroll
      for (int dt = 0; dt < 2; ++dt)
#pragma unroll
        for (int r = 0; r < 16; ++r) sc[dt][r] = 0.f;
      __builtin_amdgcn_s_setprio(1);
#pragma unroll
      for (int ks = 0; ks < 4; ++ks) {
        int sp = (2 * ks + hi) ^ (lane31 & 7);
#pragma unroll
        for (int dt = 0; dt < 2; ++dt) {
          bf16x8 kf = *(const bf16x8*)&k_lds[buf][(dt * 32 + lane31) * 64 + sp * 8];
          sc[dt] = MFMA32(kf, qf[ks], sc[dt]);
        }
      }
      __builtin_amdgcn_s_setprio(0);

      bf16x8 vf[2][4];
#pragma unroll
      for (int ks = 0; ks < 4; ++ks) {
        int sp = (2 * ks + hi) ^ (lane31 & 7);
#pragma unroll
        for (int dt = 0; dt < 2; ++dt)
          vf[dt][ks] = *(const bf16x8*)&v_lds[buf][(dt * 32 + lane31) * 64 + sp * 8];
      }

      if (t >= nkv - 2) {
#pragma unroll
        for (int dt = 0; dt < 2; ++dt)
#pragma unroll
          for (int r = 0; r < 16; ++r) {
            int kvg = t * 64 + dt * 32 + (r & 3) + 8 * (r >> 2) + 4 * hi;
            if (kvg > qrow) sc[dt][r] = -1e30f;
          }
      }

      float r16[16];
#pragma unroll
      for (int i = 0; i < 16; ++i) r16[i] = fmaxf(sc[0][i], sc[1][i]);
#pragma unroll
      for (int i = 0; i < 8; ++i) r16[i] = fmaxf(r16[i], r16[i + 8]);
#pragma unroll
      for (int i = 0; i < 4; ++i) r16[i] = fmaxf(r16[i], r16[i + 4]);
      float mx = fmaxf(fmaxf(r16[0], r16[1]), fmaxf(r16[2], r16[3]));
      mx = fmaxf(mx, __shfl_xor(mx, 32));

      // T13 defer-max: keep old normalizer while growth <= 8 (exp2 bounded by 256)
      const bool nores = __all(mx - m_run <= 8.0f);
      float mnew = nores ? m_run : fmaxf(m_run, mx);
#pragma unroll
      for (int dt = 0; dt < 2; ++dt)
#pragma unroll
        for (int r = 0; r < 16; ++r) sc[dt][r] = fexp2(sc[dt][r] - mnew);
      float s16[16];
#pragma unroll
      for (int i = 0; i < 16; ++i) s16[i] = sc[0][i] + sc[1][i];
#pragma unroll
      for (int i = 0; i < 8; ++i) s16[i] += s16[i + 8];
#pragma unroll
      for (int i = 0; i < 4; ++i) s16[i] += s16[i + 4];
      float ps = (s16[0] + s16[1]) + (s16[2] + s16[3]);
      ps += __shfl_xor(ps, 32);

      if (nores) {
        l_run += ps;
      } else {
        float alpha = fexp2(m_run - mnew);
        l_run = l_run * alpha + ps;
        m_run = mnew;
#pragma unroll
        for (int dt = 0; dt < 2; ++dt)
#pragma unroll
          for (int r = 0; r < 16; ++r) oacc[dt][r] *= alpha;
      }

      union { u32 u[4]; bf16x8 v; } pf[4];
#pragma unroll
      for (int ks = 0; ks < 4; ++ks) {
        const int sidx = ks >> 1, rb = (ks & 1) * 8;
        u32 c01 = cvt_pk_bf16(sc[sidx][rb + 0], sc[sidx][rb + 1]);
        u32 c23 = cvt_pk_bf16(sc[sidx][rb + 2], sc[sidx][rb + 3]);
        u32 c45 = cvt_pk_bf16(sc[sidx][rb + 4], sc[sidx][rb + 5]);
        u32 c67 = cvt_pk_bf16(sc[sidx][rb + 6], sc[sidx][rb + 7]);
        perm_swap(c01, c45);
        perm_swap(c23, c67);
        pf[ks].u[0] = c01; pf[ks].u[1] = c23; pf[ks].u[2] = c45; pf[ks].u[3] = c67;
      }

      __builtin_amdgcn_s_setprio(1);
#pragma unroll
      for (int dt = 0; dt < 2; ++dt)
#pragma unroll
        for (int ks = 0; ks < 4; ++ks)
          oacc[dt] = MFMA32(vf[dt][ks], pf[ks].v, oacc[dt]);
      __builtin_amdgcn_s_setprio(0);

      buf = (buf == 2) ? 0 : buf + 1;
    }

    SBAR();

    float inv = 1.f / l_run;
    u16* Ob = O + (((size_t)(b * 2048 + qrow)) << 10) + hd * 64;
#pragma unroll
    for (int dt = 0; dt < 2; ++dt)
#pragma unroll
      for (int g = 0; g < 4; ++g) {
        uint2 st;
        st.x = cvt_pk_bf16(oacc[dt][4 * g + 0] * inv, oacc[dt][4 * g + 1] * inv);
        st.y = cvt_pk_bf16(oacc[dt][4 * g + 2] * inv, oacc[dt][4 * g + 3] * inv);
        *(uint2*)&Ob[dt * 32 + g * 8 + hi * 4] = st;
      }
  }
}

// ---------- launch ----------

extern "C" void kernel_launch(void* const* d_in, const int* in_sizes, int n_in,
                              void* d_out, int out_size, void* d_ws, size_t ws_size,
                              hipStream_t stream) {
  (void)in_sizes; (void)n_in; (void)out_size; (void)ws_size;
  const float* x  = (const float*)d_in[0];
  const int* pos  = (const int*)d_in[1];
  const float* Wq = (const float*)d_in[2];
  const float* Wk = (const float*)d_in[3];
  const float* Wv = (const float*)d_in[4];
  const float* Wo = (const float*)d_in[5];
  float* out = (float*)d_out;

  const int S = 2048, D = 1024;
  const size_t M = (size_t)4 * S;          // 8192

  char* ws = (char*)d_ws;
  size_t off = 0;
  auto alloc = [&](size_t bytes) {
    void* p = ws + off;
    off += (bytes + 255) & ~(size_t)255;
    return p;
  };
  u16* xb   = (u16*)alloc(M * D * 2);
  u16* wqb  = (u16*)alloc((size_t)D * D * 2);   // wqb|wkb|wvb|wob contiguous
  u16* wkb  = (u16*)alloc((size_t)D * D * 2);
  u16* wvb  = (u16*)alloc((size_t)D * D * 2);
  u16* wob  = (u16*)alloc((size_t)D * D * 2);
  u16* Qr   = (u16*)alloc(M * D * 2);
  u16* Kr   = (u16*)alloc(M * D * 2);
  u16* Vt   = (u16*)alloc(M * D * 2);
  u16* Ob   = (u16*)alloc(M * D * 2);
  float2* csT = (float2*)alloc((size_t)S * 32 * 8);

  cast_all_k<<<12288, 256, 0, stream>>>(x, Wq, Wk, Wv, Wo, xb, wqb, wkb, wvb, wob);
  rope_table_k<<<(S * 32) / 256, 256, 0, stream>>>(pos, csT);

  // Q scale: 1/sqrt(64) folded with 1/ln2 so attention logits are in exp2 domain
  const float QSCALE = 0.125f * 1.4426950408889634f;

  gemm_qkv<<<384, 512, 0, stream>>>(xb, wqb, csT, Qr, Kr, Vt, QSCALE);
  attn_k<<<512, 256, 0, stream>>>(Qr, Kr, Vt, Ob);
  gemm_bt<<<dim3(8, (unsigned)(M / 128)), 256, 0, stream>>>(Ob, wob, out, (int)M, D, D);
}

// Round 17
// 174.321 us; speedup vs baseline: 1.2409x; 1.0360x over previous
//
#include <hip/hip_runtime.h>
#include <hip/hip_bf16.h>
#include <cstdint>
#include <cstddef>

typedef __attribute__((ext_vector_type(4))) float f32x4;
typedef __attribute__((ext_vector_type(16))) float f32x16;
typedef __attribute__((ext_vector_type(8))) short bf16x8;
typedef unsigned int u32;
typedef unsigned short u16;

// ---------- helpers ----------

__device__ __forceinline__ u16 f2bf(float x) {
  u32 u = __builtin_bit_cast(u32, x);
  u += 0x7fffu + ((u >> 16) & 1u);   // round-to-nearest-even
  return (u16)(u >> 16);
}

__device__ __forceinline__ u32 cvt_pk_bf16(float lo, float hi) {
  u32 r;
  asm("v_cvt_pk_bf16_f32 %0, %1, %2" : "=v"(r) : "v"(lo), "v"(hi));
  return r;
}

// raw 2^x (trans op; s_nop guards the trans->VALU hazard window)
__device__ __forceinline__ float fexp2(float x) {
  float r;
  asm("v_exp_f32 %0, %1\n\ts_nop 1" : "=v"(r) : "v"(x));
  return r;
}

// v_permlane32_swap_b32: a' = [a.lo | b.lo], b' = [a.hi | b.hi]
__device__ __forceinline__ void perm_swap(u32& a, u32& b) {
  asm("v_permlane32_swap_b32 %0, %1" : "+v"(a), "+v"(b));
}

// async global->LDS, 16B per lane. Dest must be wave-linear (base + lane*16).
__device__ __forceinline__ void gl_lds16(const void* g, void* l) {
  __builtin_amdgcn_global_load_lds(
      (const __attribute__((address_space(1))) u32*)(uintptr_t)g,
      (__attribute__((address_space(3))) u32*)(u32)(uintptr_t)l,
      16, 0, 0);
}

#define MFMA16(a, b, c) __builtin_amdgcn_mfma_f32_16x16x32_bf16((a), (b), (c), 0, 0, 0)
#define MFMA32(a, b, c) __builtin_amdgcn_mfma_f32_32x32x16_bf16((a), (b), (c), 0, 0, 0)
#define SBAR() do { __builtin_amdgcn_sched_barrier(0); __builtin_amdgcn_s_barrier(); \
                    __builtin_amdgcn_sched_barrier(0); } while (0)
#define SCHED_FENCE() __builtin_amdgcn_sched_barrier(0)

// ---------- fused cast fp32 -> bf16 for x + 4 weights ----------

__global__ void cast_all_k(const float* __restrict__ x, const float* __restrict__ wq,
                           const float* __restrict__ wk, const float* __restrict__ wv,
                           const float* __restrict__ wo, u16* __restrict__ xb,
                           u16* __restrict__ wqb, u16* __restrict__ wkb,
                           u16* __restrict__ wvb, u16* __restrict__ wob) {
  int blk = blockIdx.x;
  const float* s; u16* d; int i;
  if (blk < 8192)       { s = x;  d = xb;  i = blk * 256; }
  else if (blk < 9216)  { s = wq; d = wqb; i = (blk - 8192) * 256; }
  else if (blk < 10240) { s = wk; d = wkb; i = (blk - 9216) * 256; }
  else if (blk < 11264) { s = wv; d = wvb; i = (blk - 10240) * 256; }
  else                  { s = wo; d = wob; i = (blk - 11264) * 256; }
  i += threadIdx.x;
  const float4 v = reinterpret_cast<const float4*>(s)[i];
  uint2 o;
  o.x = cvt_pk_bf16(v.x, v.y);
  o.y = cvt_pk_bf16(v.z, v.w);
  reinterpret_cast<uint2*>(d)[i] = o;
}

// ---------- rope cos/sin table: [S][32] of float2(cos,sin) ----------

__global__ void rope_table_k(const int* __restrict__ pos, float2* __restrict__ cs) {
  int idx = blockIdx.x * 256 + threadIdx.x;   // S*32 = 65536
  int s = idx >> 5, i = idx & 31;
  float inv = powf(10000.0f, -(float)i * (1.0f / 32.0f));
  float ang = (float)pos[s] * inv;
  cs[idx] = float2{cosf(ang), sinf(ang)};
}

// ---------- fused QKV GEMM — 256x192, BK=64, top-wait pipeline ----------
// Grid 512 (1D, XCD-swizzled) = EXACTLY 2 placement rounds at 1 block/CU.
// LDS 112KB (A 32KB + B 24KB, double-buffered). 8 waves 2x4, wave tile 128x48,
// acc[8][3] (96 VGPR; no launch_bounds min-occupancy -> no spill).
// Protocol: tile-top vmcnt(0) (waits chunks issued a full tile earlier) ->
// s_barrier -> stage tile t+1 front-loaded into phases 0-2 -> 4 MFMA phases.

__global__ __launch_bounds__(512)
void gemm_qkv(const u16* __restrict__ A, const u16* __restrict__ B,
              const float2* __restrict__ cs, u16* __restrict__ Qr,
              u16* __restrict__ Kr, u16* __restrict__ Vt, float qscale) {
  const int K = 1024;
  __shared__ u16 a_lds[2][256 * 64];
  __shared__ u16 b_lds[2][192 * 64];

  const int tid = threadIdx.x, l = tid & 63;
  const int wid = tid >> 6;                // 0..7
  const int wr = wid >> 2, wc = wid & 3;   // wave tile 128 rows x 48 cols
  const int c = l & 15, h4 = l >> 4;

  // XCD swizzle: id&7 = XCD; bm = xcd*4 + k64/16, bn = k64%16
  const int id = blockIdx.x;               // 512
  const int k64 = id >> 3, xcd = id & 7;
  const int bm = xcd * 4 + (k64 >> 4), bn = k64 & 15;

  const u16* Ab = A + (size_t)bm * 256 * K;
  const u16* Bb = B + (size_t)bn * 192 * K;

  // A chunk ch covers rows 64ch..64ch+63 (4 chunks); B same (3 chunks)
  auto stageA = [&](int s, int chunk, int k0) {
    int t5 = chunk * 512 + tid;
    int row = t5 >> 3, slot = t5 & 7;
    int sp = slot ^ (row & 7);
    gl_lds16(Ab + (size_t)row * K + k0 + sp * 8, &a_lds[s][t5 * 8]);
  };
  auto stageB = [&](int s, int chunk, int k0) {
    int t5 = chunk * 512 + tid;
    int row = t5 >> 3, slot = t5 & 7;
    int sp = slot ^ (row & 7);
    gl_lds16(Bb + (size_t)row * K + k0 + sp * 8, &b_lds[s][t5 * 8]);
  };

  const f32x4 fz = {0.f, 0.f, 0.f, 0.f};
  f32x4 acc[8][3];
#pragma unroll
  for (int mi = 0; mi < 8; ++mi)
#pragma unroll
    for (int ni = 0; ni < 3; ++ni) acc[mi][ni] = fz;

  // prologue: issue tile 0 (7 chunks); waited at loop top
#pragma unroll
  for (int ch = 0; ch < 4; ++ch) stageA(0, ch, 0);
#pragma unroll
  for (int ch = 0; ch < 3; ++ch) stageB(0, ch, 0);

  const int nk = K >> 6;                   // 16 K-tiles
#pragma unroll 1
  for (int t = 0; t < nk; ++t) {
    const int s = t & 1;
    const int k1 = (t + 1) << 6;
    const bool st = (t + 1 < nk);

    asm volatile("s_waitcnt vmcnt(0)" ::: "memory");  // own tile-t chunks landed
    SBAR();                                           // all waves' tile-t landed;
                                                      // all waves done reading t-1
    bf16x8 bfr[3][2];
#pragma unroll
    for (int ni = 0; ni < 3; ++ni)
#pragma unroll
      for (int kk = 0; kk < 2; ++kk) {
        int row = wc * 48 + ni * 16 + c;
        int sp = (kk * 4 + h4) ^ (row & 7);
        bfr[ni][kk] = *(const bf16x8*)&b_lds[s][row * 64 + sp * 8];
      }

#pragma unroll
    for (int p = 0; p < 4; ++p) {
      bf16x8 af[2][2];
#pragma unroll
      for (int m2 = 0; m2 < 2; ++m2)
#pragma unroll
        for (int kk = 0; kk < 2; ++kk) {
          int mi = p * 2 + m2;
          int row = wr * 128 + mi * 16 + c;
          int sp = (kk * 4 + h4) ^ (row & 7);
          af[m2][kk] = *(const bf16x8*)&a_lds[s][row * 64 + sp * 8];
        }
      if (st) {                            // front-loaded: last chunk issued in p2
        if (p == 0)      { stageA(s ^ 1, 0, k1); stageA(s ^ 1, 1, k1); stageA(s ^ 1, 2, k1); }
        else if (p == 1) { stageA(s ^ 1, 3, k1); stageB(s ^ 1, 0, k1); }
        else if (p == 2) { stageB(s ^ 1, 1, k1); stageB(s ^ 1, 2, k1); }
      }
      SCHED_FENCE();
      __builtin_amdgcn_s_setprio(1);
#pragma unroll
      for (int m2 = 0; m2 < 2; ++m2)
#pragma unroll
        for (int ni = 0; ni < 3; ++ni)
#pragma unroll
          for (int kk = 0; kk < 2; ++kk)
            acc[p * 2 + m2][ni] = MFMA16(af[m2][kk], bfr[ni][kk], acc[p * 2 + m2][ni]);
      __builtin_amdgcn_s_setprio(0);
      SCHED_FENCE();
    }
  }

  // ---- epilogue: per-fragment sector (16-wide frags are sector-uniform) ----
  const int colg0 = bn * 192 + wc * 48;

#pragma unroll
  for (int mi = 0; mi < 8; ++mi) {
    int row0 = bm * 256 + wr * 128 + mi * 16 + 4 * h4;
    int b_ = row0 >> 11, s0 = row0 & 2047;   // rows row0..row0+3 in same batch
#pragma unroll
    for (int ni = 0; ni < 3; ++ni) {
      int cv = colg0 + ni * 16 + c;          // global col in [0,3072)
      int sector = cv >> 10;                  // wave-uniform per fragment
      int i2s = cv & 1023;
      int hh = i2s >> 6, i2 = cv & 63;
      f32x4 v = acc[mi][ni];
      if (sector == 2) {
        uint2 st;
        st.x = cvt_pk_bf16(v[0], v[1]);
        st.y = cvt_pk_bf16(v[2], v[3]);
        *(uint2*)&Vt[(((size_t)b_ * 16 + hh) << 17) + ((size_t)i2 << 11) + s0] = st;
      } else {
        u16* dst = sector ? Kr : Qr;
        const float scale = sector ? 1.0f : qscale;
        f32x4 pv;
#pragma unroll
        for (int j = 0; j < 4; ++j) pv[j] = __shfl_xor(v[j], 1);
        if (!(l & 1)) {                      // even lanes write the (even,odd) pair
#pragma unroll
          for (int j = 0; j < 4; ++j) {
            int s = s0 + j;
            float2 tt = cs[(s << 5) + (i2 >> 1)];
            float oe = (v[j] * tt.x - pv[j] * tt.y) * scale;
            float oo = (v[j] * tt.y + pv[j] * tt.x) * scale;
            *(u32*)&dst[(((size_t)(b_ * 16 + hh) * 2048 + s) << 6) + i2] =
                cvt_pk_bf16(oe, oo);
          }
        }
      }
    }
  }
}

// ---------- GEMM: C(MxN fp32) = A(MxK bf16) * B^T — 3-slot counted-vmcnt ----------

__global__ __launch_bounds__(256, 3)
void gemm_bt(const u16* __restrict__ A, const u16* __restrict__ B,
             float* __restrict__ C, int M, int N, int K) {
  __shared__ u16 a_lds[3][128 * 32];
  __shared__ u16 b_lds[3][128 * 32];
  const int tid = threadIdx.x;
  const int l = tid & 63;
  const int w = tid >> 6;
  const int wm = w >> 1, wn = w & 1;
  const int bm = blockIdx.y, bn = blockIdx.x;
  const int c = l & 15, h4 = l >> 4;

  const u16* Ab = A + (size_t)bm * 128 * K;
  const u16* Bb = B + (size_t)bn * 128 * K;

  auto stage = [&](int sl, int k0) {
#pragma unroll
    for (int half = 0; half < 2; ++half) {
      int t = half * 256 + tid;
      int row = t >> 2, slot = t & 3;
      int sp = slot ^ ((row >> 1) & 3);
      gl_lds16(Ab + (size_t)row * K + k0 + sp * 8, &a_lds[sl][t * 8]);
      gl_lds16(Bb + (size_t)row * K + k0 + sp * 8, &b_lds[sl][t * 8]);
    }
  };

  const f32x4 fz = {0.f, 0.f, 0.f, 0.f};
  f32x4 acc[4][4];
#pragma unroll
  for (int mi = 0; mi < 4; ++mi)
#pragma unroll
    for (int ni = 0; ni < 4; ++ni) acc[mi][ni] = fz;

  const int nk = K >> 5;
  stage(0, 0);
  stage(1, 32);

  int sl = 0;
#pragma unroll 1
  for (int t = 0; t < nk; ++t) {
    if (t + 2 < nk) {
      int s2 = sl + 2; if (s2 >= 3) s2 -= 3;
      stage(s2, (t + 2) * 32);
      __builtin_amdgcn_sched_barrier(0);
      asm volatile("s_waitcnt vmcnt(8)" ::: "memory");
    } else if (t + 1 < nk) {
      asm volatile("s_waitcnt vmcnt(4)" ::: "memory");
    } else {
      asm volatile("s_waitcnt vmcnt(0)" ::: "memory");
    }
    SBAR();

    bf16x8 af[4], bf[4];
#pragma unroll
    for (int mi = 0; mi < 4; ++mi) {
      int row = wm * 64 + mi * 16 + c;
      int sp = h4 ^ ((row >> 1) & 3);
      af[mi] = *(const bf16x8*)&a_lds[sl][row * 32 + sp * 8];
    }
#pragma unroll
    for (int ni = 0; ni < 4; ++ni) {
      int row = wn * 64 + ni * 16 + c;
      int sp = h4 ^ ((row >> 1) & 3);
      bf[ni] = *(const bf16x8*)&b_lds[sl][row * 32 + sp * 8];
    }
    __builtin_amdgcn_s_setprio(1);
#pragma unroll
    for (int mi = 0; mi < 4; ++mi)
#pragma unroll
      for (int ni = 0; ni < 4; ++ni)
        acc[mi][ni] = MFMA16(af[mi], bf[ni], acc[mi][ni]);
    __builtin_amdgcn_s_setprio(0);

    sl = (sl == 2) ? 0 : sl + 1;
  }

#pragma unroll
  for (int mi = 0; mi < 4; ++mi) {
    int rbase = bm * 128 + wm * 64 + mi * 16 + ((l >> 4) << 2);
#pragma unroll
    for (int ni = 0; ni < 4; ++ni) {
      int col = bn * 128 + wn * 64 + ni * 16 + (l & 15);
      f32x4 v = acc[mi][ni];
#pragma unroll
      for (int j = 0; j < 4; ++j)
        C[(size_t)(rbase + j) * N + col] = v[j];
    }
  }
}

// ---------- causal flash attention: 32x32 MFMA, 4 waves, 3-slot pipeline ----------

__global__ __launch_bounds__(256, 2)
void attn_k(const u16* __restrict__ Q, const u16* __restrict__ K,
            const u16* __restrict__ V, u16* __restrict__ O) {
  const int S = 2048;
  __shared__ u16 k_lds[3][64 * 64];
  __shared__ u16 v_lds[3][64 * 64];       // [dk][kv]

  const int tid = threadIdx.x, l = tid & 63, w = tid >> 6;
  const int lane31 = l & 31, hi = l >> 5;

  const int wg = blockIdx.x;                       // 512
  const int idx = (wg & 7) * 64 + (wg >> 3);
  const int bh = idx >> 3, pairI = idx & 7;

  const u16* Kb = K + (size_t)bh * S * 64;
  const u16* Vb = V + (size_t)bh * 64 * S;
  const int b = bh >> 4, hd = bh & 15;

  auto stageKV = [&](int bq, int kv0) {
#pragma unroll
    for (int half = 0; half < 2; ++half) {
      int t = half * 256 + tid;
      int row = t >> 3, slot = t & 7;
      int sp = slot ^ (row & 7);
      gl_lds16(Kb + (size_t)(kv0 + row) * 64 + sp * 8, &k_lds[bq][t * 8]);
      gl_lds16(Vb + (size_t)row * S + kv0 + sp * 8, &v_lds[bq][t * 8]);
    }
  };

#pragma unroll 1
  for (int ph = 0; ph < 2; ++ph) {
    const int qi = ph ? (15 - pairI) : pairI;
    const int q0 = qi * 128;
    const int nkv = 2 * qi + 2;
    const int qrow = q0 + w * 32 + lane31;
    const u16* Qp = Q + ((size_t)bh * S + qrow) * 64;

    bf16x8 qf[4];
#pragma unroll
    for (int ks = 0; ks < 4; ++ks)
      qf[ks] = *(const bf16x8*)(Qp + ks * 16 + hi * 8);
    __builtin_amdgcn_sched_barrier(0);
    stageKV(0, 0);
    stageKV(1, 64);

    f32x16 oacc[2];
#pragma unroll
    for (int dt = 0; dt < 2; ++dt)
#pragma unroll
      for (int r = 0; r < 16; ++r) oacc[dt][r] = 0.f;
    float m_run = -1e30f, l_run = 0.f;

    int buf = 0;
#pragma unroll 1
    for (int t = 0; t < nkv; ++t) {
      if (t + 2 < nkv) {
        int b2 = buf + 2; if (b2 >= 3) b2 -= 3;
        stageKV(b2, (t + 2) * 64);
        __builtin_amdgcn_sched_barrier(0);
        asm volatile("s_waitcnt vmcnt(8)" ::: "memory");
      } else if (t + 1 < nkv) {
        asm volatile("s_waitcnt vmcnt(4)" ::: "memory");
      } else {
        asm volatile("s_waitcnt vmcnt(0)" ::: "memory");
      }
      SBAR();

      f32x16 sc[2];
#pragma unroll
      for (int dt = 0; dt < 2; ++dt)
#pragma unroll
        for (int r = 0; r < 16; ++r) sc[dt][r] = 0.f;
      __builtin_amdgcn_s_setprio(1);
#pragma unroll
      for (int ks = 0; ks < 4; ++ks) {
        int sp = (2 * ks + hi) ^ (lane31 & 7);
#pragma unroll
        for (int dt = 0; dt < 2; ++dt) {
          bf16x8 kf = *(const bf16x8*)&k_lds[buf][(dt * 32 + lane31) * 64 + sp * 8];
          sc[dt] = MFMA32(kf, qf[ks], sc[dt]);
        }
      }
      __builtin_amdgcn_s_setprio(0);

      bf16x8 vf[2][4];
#pragma unroll
      for (int ks = 0; ks < 4; ++ks) {
        int sp = (2 * ks + hi) ^ (lane31 & 7);
#pragma unroll
        for (int dt = 0; dt < 2; ++dt)
          vf[dt][ks] = *(const bf16x8*)&v_lds[buf][(dt * 32 + lane31) * 64 + sp * 8];
      }

      if (t >= nkv - 2) {
#pragma unroll
        for (int dt = 0; dt < 2; ++dt)
#pragma unroll
          for (int r = 0; r < 16; ++r) {
            int kvg = t * 64 + dt * 32 + (r & 3) + 8 * (r >> 2) + 4 * hi;
            if (kvg > qrow) sc[dt][r] = -1e30f;
          }
      }

      float r16[16];
#pragma unroll
      for (int i = 0; i < 16; ++i) r16[i] = fmaxf(sc[0][i], sc[1][i]);
#pragma unroll
      for (int i = 0; i < 8; ++i) r16[i] = fmaxf(r16[i], r16[i + 8]);
#pragma unroll
      for (int i = 0; i < 4; ++i) r16[i] = fmaxf(r16[i], r16[i + 4]);
      float mx = fmaxf(fmaxf(r16[0], r16[1]), fmaxf(r16[2], r16[3]));
      mx = fmaxf(mx, __shfl_xor(mx, 32));

      // T13 defer-max: keep old normalizer while growth <= 8 (exp2 bounded by 256)
      const bool nores = __all(mx - m_run <= 8.0f);
      float mnew = nores ? m_run : fmaxf(m_run, mx);
#pragma unroll
      for (int dt = 0; dt < 2; ++dt)
#pragma unroll
        for (int r = 0; r < 16; ++r) sc[dt][r] = fexp2(sc[dt][r] - mnew);
      float s16[16];
#pragma unroll
      for (int i = 0; i < 16; ++i) s16[i] = sc[0][i] + sc[1][i];
#pragma unroll
      for (int i = 0; i < 8; ++i) s16[i] += s16[i + 8];
#pragma unroll
      for (int i = 0; i < 4; ++i) s16[i] += s16[i + 4];
      float ps = (s16[0] + s16[1]) + (s16[2] + s16[3]);
      ps += __shfl_xor(ps, 32);

      if (nores) {
        l_run += ps;
      } else {
        float alpha = fexp2(m_run - mnew);
        l_run = l_run * alpha + ps;
        m_run = mnew;
#pragma unroll
        for (int dt = 0; dt < 2; ++dt)
#pragma unroll
          for (int r = 0; r < 16; ++r) oacc[dt][r] *= alpha;
      }

      union { u32 u[4]; bf16x8 v; } pf[4];
#pragma unroll
      for (int ks = 0; ks < 4; ++ks) {
        const int sidx = ks >> 1, rb = (ks & 1) * 8;
        u32 c01 = cvt_pk_bf16(sc[sidx][rb + 0], sc[sidx][rb + 1]);
        u32 c23 = cvt_pk_bf16(sc[sidx][rb + 2], sc[sidx][rb + 3]);
        u32 c45 = cvt_pk_bf16(sc[sidx][rb + 4], sc[sidx][rb + 5]);
        u32 c67 = cvt_pk_bf16(sc[sidx][rb + 6], sc[sidx][rb + 7]);
        perm_swap(c01, c45);
        perm_swap(c23, c67);
        pf[ks].u[0] = c01; pf[ks].u[1] = c23; pf[ks].u[2] = c45; pf[ks].u[3] = c67;
      }

      __builtin_amdgcn_s_setprio(1);
#pragma unroll
      for (int dt = 0; dt < 2; ++dt)
#pragma unroll
        for (int ks = 0; ks < 4; ++ks)
          oacc[dt] = MFMA32(vf[dt][ks], pf[ks].v, oacc[dt]);
      __builtin_amdgcn_s_setprio(0);

      buf = (buf == 2) ? 0 : buf + 1;
    }

    SBAR();

    float inv = 1.f / l_run;
    u16* Ob = O + (((size_t)(b * 2048 + qrow)) << 10) + hd * 64;
#pragma unroll
    for (int dt = 0; dt < 2; ++dt)
#pragma unroll
      for (int g = 0; g < 4; ++g) {
        uint2 st;
        st.x = cvt_pk_bf16(oacc[dt][4 * g + 0] * inv, oacc[dt][4 * g + 1] * inv);
        st.y = cvt_pk_bf16(oacc[dt][4 * g + 2] * inv, oacc[dt][4 * g + 3] * inv);
        *(uint2*)&Ob[dt * 32 + g * 8 + hi * 4] = st;
      }
  }
}

// ---------- launch ----------

extern "C" void kernel_launch(void* const* d_in, const int* in_sizes, int n_in,
                              void* d_out, int out_size, void* d_ws, size_t ws_size,
                              hipStream_t stream) {
  (void)in_sizes; (void)n_in; (void)out_size; (void)ws_size;
  const float* x  = (const float*)d_in[0];
  const int* pos  = (const int*)d_in[1];
  const float* Wq = (const float*)d_in[2];
  const float* Wk = (const float*)d_in[3];
  const float* Wv = (const float*)d_in[4];
  const float* Wo = (const float*)d_in[5];
  float* out = (float*)d_out;

  const int S = 2048, D = 1024;
  const size_t M = (size_t)4 * S;          // 8192

  char* ws = (char*)d_ws;
  size_t off = 0;
  auto alloc = [&](size_t bytes) {
    void* p = ws + off;
    off += (bytes + 255) & ~(size_t)255;
    return p;
  };
  u16* xb   = (u16*)alloc(M * D * 2);
  u16* wqb  = (u16*)alloc((size_t)D * D * 2);   // wqb|wkb|wvb|wob contiguous
  u16* wkb  = (u16*)alloc((size_t)D * D * 2);
  u16* wvb  = (u16*)alloc((size_t)D * D * 2);
  u16* wob  = (u16*)alloc((size_t)D * D * 2);
  u16* Qr   = (u16*)alloc(M * D * 2);
  u16* Kr   = (u16*)alloc(M * D * 2);
  u16* Vt   = (u16*)alloc(M * D * 2);
  u16* Ob   = (u16*)alloc(M * D * 2);
  float2* csT = (float2*)alloc((size_t)S * 32 * 8);

  cast_all_k<<<12288, 256, 0, stream>>>(x, Wq, Wk, Wv, Wo, xb, wqb, wkb, wvb, wob);
  rope_table_k<<<(S * 32) / 256, 256, 0, stream>>>(pos, csT);

  // Q scale: 1/sqrt(64) folded with 1/ln2 so attention logits are in exp2 domain
  const float QSCALE = 0.125f * 1.4426950408889634f;

  gemm_qkv<<<512, 512, 0, stream>>>(xb, wqb, csT, Qr, Kr, Vt, QSCALE);
  attn_k<<<512, 256, 0, stream>>>(Qr, Kr, Vt, Ob);
  gemm_bt<<<dim3(8, (unsigned)(M / 128)), 256, 0, stream>>>(Ob, wob, out, (int)M, D, D);
}